// Round 3
// baseline (135.594 us; speedup 1.0000x reference)
//
#include <hip/hip_runtime.h>

#define Bsz 8
#define Cn  4
#define Hn  64
#define Wn  2048
#define HW  (Hn*Wn)
#define NPIX (Bsz*HW)

#define TW 64
#define TH 8
#define HALO_W (TW+4)         // 68
#define HALO_H (TH+2)         // 10
#define NHALO (HALO_W*HALO_H) // 680

// Gaussian stencil exp(-(dh^2+dw^2)/(2*0.9^2)), center zeroed.
#define G1 0.53940824f   // pd=1
#define G2 0.29096127f   // pd=2
#define G4 0.08465836f   // pd=4
#define G5 0.04566536f   // pd=5

__device__ __forceinline__ float4 f4fma(float a, const float4& v, const float4& acc) {
    return make_float4(fmaf(a, v.x, acc.x), fmaf(a, v.y, acc.y),
                       fmaf(a, v.z, acc.z), fmaf(a, v.w, acc.w));
}

__global__ __launch_bounds__(256) void pack_xm(const float* __restrict__ xyz,
                                               const float* __restrict__ mask,
                                               float4* __restrict__ XM) {
    int t = blockIdx.x * 256 + threadIdx.x;     // 0..NPIX-1
    int p = t & (HW - 1);
    int b = t >> 17;
    size_t xb = (size_t)b * 3 * HW + p;
    XM[t] = make_float4(xyz[xb], xyz[xb + HW], xyz[xb + 2 * HW],
                        mask[(size_t)b * HW + p]);
}

template<bool OUT_PLANAR>
__device__ __forceinline__ void epilogue(const float4& ksm, const float4& app, float mc,
                                         const float* __restrict__ unary,
                                         size_t qoff, size_t poff,
                                         const float* __restrict__ wa,
                                         const float* __restrict__ wsm,
                                         const float* __restrict__ compat,
                                         float* __restrict__ Op, float4* __restrict__ Oi) {
    float wk[4] = { ksm.x * (wsm[0] + wa[0] * (app.x * mc)),
                    ksm.y * (wsm[1] + wa[1] * (app.y * mc)),
                    ksm.z * (wsm[2] + wa[2] * (app.z * mc)),
                    ksm.w * (wsm[3] + wa[3] * (app.w * mc)) };
    float pw[4];
#pragma unroll
    for (int o = 0; o < 4; ++o)
        pw[o] = compat[o * 4 + 0] * wk[0] + compat[o * 4 + 1] * wk[1] +
                compat[o * 4 + 2] * wk[2] + compat[o * 4 + 3] * wk[3];
    if (OUT_PLANAR) {
#pragma unroll
        for (int o = 0; o < 4; ++o)
            Op[qoff + (size_t)o * HW] = unary[qoff + (size_t)o * HW] - pw[o];
    } else {
        float4 u = make_float4(unary[qoff], unary[qoff + HW],
                               unary[qoff + 2 * HW], unary[qoff + 3 * HW]);
        Oi[poff] = make_float4(u.x - pw[0], u.y - pw[1], u.z - pw[2], u.w - pw[3]);
    }
}

template<bool IN_PLANAR, bool OUT_PLANAR>
__global__ __launch_bounds__(256) void crf_iter(const float* __restrict__ Qp,
                                                const float4* __restrict__ Qi,
                                                const float* __restrict__ unary,
                                                const float4* __restrict__ XM,
                                                const float* __restrict__ wa,
                                                const float* __restrict__ wsm,
                                                const float* __restrict__ compat,
                                                float* __restrict__ Op,
                                                float4* __restrict__ Oi) {
    __shared__ float4 Sl[NHALO];
    __shared__ float4 Xl[NHALO];

    const int tid = threadIdx.x;
    const int w0 = blockIdx.x * TW;
    const int h0 = blockIdx.y * TH;
    const int b  = blockIdx.z;

    const size_t qbase = (size_t)b * Cn * HW;
    const size_t pbase = (size_t)b * HW;

    // ---- stage softmax(Q) and (xyz,mask) halo into LDS ----
#pragma unroll
    for (int k = 0; k < 3; ++k) {
        int i = tid + k * 256;
        if (i < NHALO) {
            int hr = i / HALO_W;
            int hc = i - hr * HALO_W;
            int gh = h0 + hr - 1;
            int gw = w0 + hc - 2;
            float4 s  = make_float4(0.f, 0.f, 0.f, 0.f);
            float4 xm = make_float4(0.f, 0.f, 0.f, 0.f);
            if (gh >= 0 && gh < Hn && gw >= 0 && gw < Wn) {
                size_t p = (size_t)gh * Wn + gw;
                float q0, q1, q2, q3;
                if (IN_PLANAR) {
                    q0 = Qp[qbase + p];
                    q1 = Qp[qbase + p + HW];
                    q2 = Qp[qbase + p + 2 * HW];
                    q3 = Qp[qbase + p + 3 * HW];
                } else {
                    float4 q = Qi[pbase + p];
                    q0 = q.x; q1 = q.y; q2 = q.z; q3 = q.w;
                }
                float mx = fmaxf(fmaxf(q0, q1), fmaxf(q2, q3));
                float e0 = __expf(q0 - mx), e1 = __expf(q1 - mx);
                float e2 = __expf(q2 - mx), e3 = __expf(q3 - mx);
                float inv = 1.0f / (e0 + e1 + e2 + e3);
                s  = make_float4(e0 * inv, e1 * inv, e2 * inv, e3 * inv);
                xm = XM[pbase + p];
            }
            Sl[i] = s;
            Xl[i] = xm;
        }
    }
    __syncthreads();

    // ---- 2 vertical px per thread ----
    const int lane = tid & 63;
    const int tr = tid >> 6;
    const int r0 = 2 * tr;                    // tile-local row of px0
    const int lw = lane + 2;

    const float4 xc0 = Xl[(r0 + 1) * HALO_W + lw];
    const float4 xc1 = Xl[(r0 + 2) * HALO_W + lw];

    float4 ksm0 = make_float4(0,0,0,0), app0 = make_float4(0,0,0,0);
    float4 ksm1 = make_float4(0,0,0,0), app1 = make_float4(0,0,0,0);

    const float Gt[3][5] = {
        {G5, G2, G1, G2, G5},
        {G4, G1, 0.f, G1, G4},
        {G5, G2, G1, G2, G5}};

#pragma unroll
    for (int j = 0; j < 4; ++j) {             // window row (halo coord r0+j)
        const int rbase = (r0 + j) * HALO_W + lw;
        float4 s[5], x[5];
#pragma unroll
        for (int d = 0; d < 5; ++d) {
            s[d] = Sl[rbase + d - 2];
            x[d] = Xl[rbase + d - 2];
        }
#pragma unroll
        for (int d = 0; d < 5; ++d) {
            if (j <= 2 && !(j == 1 && d == 2)) {     // px0: dh = j-1
                const float g = Gt[j][d];
                ksm0 = f4fma(g, s[d], ksm0);
                float dx = x[d].x - xc0.x, dy = x[d].y - xc0.y, dz = x[d].z - xc0.z;
                float bm = __expf(-2222.2222f * (dx*dx + dy*dy + dz*dz)) * x[d].w;
                app0 = f4fma(bm, s[d], app0);
            }
            if (j >= 1 && !(j == 2 && d == 2)) {     // px1: dh = j-2
                const float g = Gt[j - 1][d];
                ksm1 = f4fma(g, s[d], ksm1);
                float dx = x[d].x - xc1.x, dy = x[d].y - xc1.y, dz = x[d].z - xc1.z;
                float bm = __expf(-2222.2222f * (dx*dx + dy*dy + dz*dz)) * x[d].w;
                app1 = f4fma(bm, s[d], app1);
            }
        }
    }

    const int gw = w0 + lane;
    const int gh0 = h0 + r0;
    {
        size_t p = (size_t)gh0 * Wn + gw;
        epilogue<OUT_PLANAR>(ksm0, app0, xc0.w, unary, qbase + p, pbase + p,
                             wa, wsm, compat, Op, Oi);
    }
    {
        size_t p = (size_t)(gh0 + 1) * Wn + gw;
        epilogue<OUT_PLANAR>(ksm1, app1, xc1.w, unary, qbase + p, pbase + p,
                             wa, wsm, compat, Op, Oi);
    }
}

extern "C" void kernel_launch(void* const* d_in, const int* in_sizes, int n_in,
                              void* d_out, int out_size, void* d_ws, size_t ws_size,
                              hipStream_t stream) {
    const float* unary  = (const float*)d_in[0];
    const float* xyz    = (const float*)d_in[1];
    const float* mask   = (const float*)d_in[2];
    const float* wa     = (const float*)d_in[3];
    const float* wsm    = (const float*)d_in[4];
    const float* compat = (const float*)d_in[5];
    float* outp = (float*)d_out;

    float4* XM = (float4*)d_ws;                       // 16 MiB
    float4* Q1 = XM + (size_t)NPIX;                   // 16 MiB
    float4* Q2 = Q1 + (size_t)NPIX;                   // 16 MiB

    dim3 grid(Wn / TW, Hn / TH, Bsz), blk(256);

    pack_xm<<<dim3(NPIX / 256), blk, 0, stream>>>(xyz, mask, XM);

    crf_iter<true, false><<<grid, blk, 0, stream>>>(unary, nullptr, unary, XM,
                                                    wa, wsm, compat, nullptr, Q1);
    crf_iter<false, false><<<grid, blk, 0, stream>>>(nullptr, Q1, unary, XM,
                                                     wa, wsm, compat, nullptr, Q2);
    crf_iter<false, true><<<grid, blk, 0, stream>>>(nullptr, Q2, unary, XM,
                                                    wa, wsm, compat, outp, nullptr);
}